// Round 1
// 509.876 us; speedup vs baseline: 1.0187x; 1.0187x over previous
//
#include <hip/hip_runtime.h>
#include <stdint.h>

// Problem constants (from reference)
constexpr int BB = 64, TT = 200;
constexpr int M  = BB * TT;          // 12800 rows
constexpr int DSEM = 768, DPR = 384;
constexpr int Kd = DSEM + DPR;       // 1152
constexpr int Nd = 2048;             // d_model
constexpr int NUM_ITEMS = 100000;
constexpr int BK = 64;               // K-tile

constexpr int GATHER_BLOCKS = (M * Kd / 8) / 256;   // 7200 (worst case, ~half exit)
constexpr int WCONV_BLOCKS  = (Nd * Kd / 8) / 256;  // 1152
constexpr int GEMM_BLOCKS   = (M / 128) * (Nd / 128); // 1600 (worst case)
constexpr int ZB            = 256;                  // zero-fill blocks appended to gemm grid

typedef short bf16x8 __attribute__((ext_vector_type(8)));  // 8 bf16 (4 VGPRs)
typedef unsigned short u16x8 __attribute__((ext_vector_type(8)));
typedef float f32x4  __attribute__((ext_vector_type(4)));

__device__ __forceinline__ unsigned short f2bf(float f) {
  union { float f; uint32_t u; } v; v.f = f;
  uint32_t u = v.u;
  u += 0x7fffu + ((u >> 16) & 1u);   // RNE
  return (unsigned short)(u >> 16);
}

// ---- K1: single-block stable compaction (no atomics, deterministic) + amask/tok.
// ~50% of rows are padding (lengths ~ U{1..200}); compacting halves GEMM work.
__global__ __launch_bounds__(1024) void compact_kernel(
    const int* __restrict__ ids,
    int* __restrict__ cid,    // [cnt0] compacted item ids
    int* __restrict__ orig,   // [cnt0] compact row -> original row
    int* __restrict__ inv,    // [cnt1] invalid original rows
    int* __restrict__ cnt,    // cnt[0]=valid count, cnt[1]=invalid count
    float* __restrict__ amask,
    float* __restrict__ tok) {
  __shared__ int wb_v[16], wb_i[16];
  __shared__ int base_v, base_i;
  const int tid  = threadIdx.x;
  const int wave = tid >> 6;
  const int lane = tid & 63;
  if (tid == 0) { base_v = 0; base_i = 0; }
  __syncthreads();
  const unsigned long long below = (lane == 0) ? 0ull : (~0ull >> (64 - lane));
  for (int r0 = 0; r0 < M; r0 += 1024) {
    const int i = r0 + tid;
    int id = -1;
    if (i < M) id = ids[i];
    const bool valid   = (id >= 0) && (id < NUM_ITEMS);
    const bool invalidRow = (i < M) && !valid;
    const unsigned long long mv = __ballot(valid);
    const unsigned long long mi = __ballot(invalidRow);
    if (lane == 0) { wb_v[wave] = __popcll(mv); wb_i[wave] = __popcll(mi); }
    __syncthreads();
    if (tid == 0) {            // serial exclusive scan over 16 wave counts
      int av = base_v, ai = base_i;
#pragma unroll
      for (int w = 0; w < 16; ++w) {
        int tv = wb_v[w], ti = wb_i[w];
        wb_v[w] = av; wb_i[w] = ai;
        av += tv; ai += ti;
      }
      base_v = av; base_i = ai;
    }
    __syncthreads();
    if (i < M) {
      amask[i] = valid ? 1.0f : 0.0f;
      tok[i]   = valid ? (float)id : -1.0f;   // id < 2^24: exact in f32
      if (valid) {
        const int s = wb_v[wave] + __popcll(mv & below);
        cid[s]  = id;
        orig[s] = i;
      } else {
        const int s = wb_i[wave] + __popcll(mi & below);
        inv[s] = i;
      }
    }
    __syncthreads();   // protect wb_* reuse next round
  }
  if (tid == 0) { cnt[0] = base_v; cnt[1] = base_i; }
}

// ---- K2: gather VALID rows only into compact A (bf16) | proj_w -> bf16
__global__ void prep2_kernel(const int* __restrict__ cid,
                             const int* __restrict__ cnt,
                             const float* __restrict__ Esem,
                             const float* __restrict__ vpr,
                             const float* __restrict__ pw,
                             unsigned short* __restrict__ A,
                             unsigned short* __restrict__ Wb) {
  const int b = blockIdx.x;
  const int tid = threadIdx.x;
  if (b < GATHER_BLOCKS) {
    // 8 elems/thread: 144 chunks per compact row; chunk 96 splits sem|prompt exactly.
    const int cnt0 = cnt[0];
    unsigned g = (unsigned)b * 256u + tid;
    unsigned row = g / 144u;
    if ((int)row >= cnt0) return;          // no barriers in this kernel: safe divergence
    unsigned col = (g - row * 144u) * 8u;
    const int id = cid[row];               // guaranteed valid
    const float* src = (col < (unsigned)DSEM)
                         ? (Esem + (size_t)id * DSEM + col)
                         : (vpr  + (size_t)id * DPR  + (col - DSEM));
    float4 v0 = *(const float4*)src;
    float4 v1 = *(const float4*)(src + 4);
    u16x8 o;
    o[0] = f2bf(v0.x); o[1] = f2bf(v0.y); o[2] = f2bf(v0.z); o[3] = f2bf(v0.w);
    o[4] = f2bf(v1.x); o[5] = f2bf(v1.y); o[6] = f2bf(v1.z); o[7] = f2bf(v1.w);
    *(u16x8*)(A + (size_t)row * Kd + col) = o;   // single 16B store
  } else {
    int g = (b - GATHER_BLOCKS) * 256 + tid;
    int e = g * 8;
    float4 v0 = *(const float4*)(pw + e);
    float4 v1 = *(const float4*)(pw + e + 4);
    u16x8 o;
    o[0] = f2bf(v0.x); o[1] = f2bf(v0.y); o[2] = f2bf(v0.z); o[3] = f2bf(v0.w);
    o[4] = f2bf(v1.x); o[5] = f2bf(v1.y); o[6] = f2bf(v1.z); o[7] = f2bf(v1.w);
    *(u16x8*)(Wb + e) = o;
  }
}

// ---- async 16B global->LDS (wave-uniform LDS base + lane*16 semantics)
__device__ __forceinline__ void async16(const void* gsrc, void* ldst) {
  __builtin_amdgcn_global_load_lds(
      (const __attribute__((address_space(1))) unsigned int*)gsrc,
      (__attribute__((address_space(3))) unsigned int*)ldst,
      16, 0, 0);
}

// ---- K3: C_compact[cnt0,Nd] = A @ Wb^T (bf16 MFMA), scattered to out rows,
//          plus ZB appended blocks zero-filling invalid out rows.
// 128x128 tile, BK=64 (18 K-iters), 4 waves 2x2, wave = 64x64 via 4x4 MFMA 16x16x32.
// LDS XOR chunk swizzle: LDS chunk c of row r holds global chunk (c ^ (r&7)).
// XCD swizzle: xcd k = b&7 owns n-tiles {k, k+8}; block pairs the two n-blocks
// of one m-strip so the A-strip L2-hits on its second read.
__global__ __launch_bounds__(256) void gemm_kernel(const unsigned short* __restrict__ A,
                                                   const unsigned short* __restrict__ Wb,
                                                   const int* __restrict__ orig,
                                                   const int* __restrict__ inv,
                                                   const int* __restrict__ cnt,
                                                   float* __restrict__ C) {
  __shared__ __align__(16) unsigned short lds_a[128 * BK];  // 16 KB
  __shared__ __align__(16) unsigned short lds_b[128 * BK];  // 16 KB

  const int tid = threadIdx.x;

  if (blockIdx.x >= GEMM_BLOCKS) {
    // zero-fill invalid output rows: one 8KB row per block-iteration, coalesced
    const int zb   = blockIdx.x - GEMM_BLOCKS;
    const int ninv = cnt[1];
    const float4 z4 = {0.f, 0.f, 0.f, 0.f};
    for (int v = zb; v < ninv; v += ZB) {
      float* dst = C + (size_t)inv[v] * Nd + tid * 8;
      *(float4*)dst       = z4;
      *(float4*)(dst + 4) = z4;
    }
    return;
  }

  const int cnt0   = cnt[0];
  const int strips = (cnt0 + 127) >> 7;

  const int b  = blockIdx.x;       // 0..1599
  const int k8 = b & 7;
  const int i  = b >> 3;           // 0..199
  if ((i >> 1) >= strips) return;  // block-uniform: inactive strip, exit before barriers
  const int m0 = (i >> 1) * 128;                // compact m-strip
  const int n0 = (k8 + 8 * (i & 1)) * 128;      // n-tile: {k8, k8+8}

  const int lane = tid & 63;
  const int wave = tid >> 6;
  const int wm = wave >> 1, wn = wave & 1;
  const int quad = lane >> 4, lm = lane & 15;

  // staging: slot idx = r*256 + tid -> LDS row = idx>>3, chunk = idx&7 (8 elems)
  const int srow   = tid >> 3;   // + r*32
  const int schunk = tid & 7;

  f32x4 acc[4][4];
#pragma unroll
  for (int i2 = 0; i2 < 4; ++i2)
#pragma unroll
    for (int j = 0; j < 4; ++j) acc[i2][j] = (f32x4){0.f, 0.f, 0.f, 0.f};

  for (int kt = 0; kt < Kd / BK; ++kt) {
    const int k0 = kt * BK;
#pragma unroll
    for (int r = 0; r < 4; ++r) {
      const int row = r * 32 + srow;
      const int gch = schunk ^ (row & 7);      // XOR swizzle (global side is per-lane)
      const unsigned short* ga = A + (size_t)(m0 + row) * Kd + k0 + gch * 8;
      async16(ga, lds_a + (size_t)(r * 256 + wave * 64) * 8);  // wave-uniform base
      const unsigned short* gb = Wb + (size_t)(n0 + row) * Kd + k0 + gch * 8;
      async16(gb, lds_b + (size_t)(r * 256 + wave * 64) * 8);
    }
    __syncthreads();

#pragma unroll
    for (int h = 0; h < 2; ++h) {              // two 32-wide k-slabs per BK=64
      bf16x8 af[4], bfr[4];
#pragma unroll
      for (int mi = 0; mi < 4; ++mi) {
        const int row = wm * 64 + mi * 16 + lm;
        af[mi] = *(const bf16x8*)(lds_a + row * BK + ((h * 4 + quad) ^ (row & 7)) * 8);
      }
#pragma unroll
      for (int ni = 0; ni < 4; ++ni) {
        const int row = wn * 64 + ni * 16 + lm;
        bfr[ni] = *(const bf16x8*)(lds_b + row * BK + ((h * 4 + quad) ^ (row & 7)) * 8);
      }
#pragma unroll
      for (int mi = 0; mi < 4; ++mi)
#pragma unroll
        for (int ni = 0; ni < 4; ++ni)
          acc[mi][ni] = __builtin_amdgcn_mfma_f32_16x16x32_bf16(af[mi], bfr[ni], acc[mi][ni], 0, 0, 0);
    }
    __syncthreads();
  }

  // ---- epilogue: same-wave LDS transpose -> coalesced dwordx4 stores,
  //      scattered through orig[] (stable compaction => monotone rows).
  float* lw = (float*)lds_a + wave * 1024;   // 16 rows x 64 cols f32, wave-private
  const int r4  = lane >> 4;     // 0..3
  const int c16 = lane & 15;     // 0..15
#pragma unroll
  for (int mi = 0; mi < 4; ++mi) {
    // C/D layout: col = lane&15, row = quad*4 + reg  [measured m89/m91]
#pragma unroll
    for (int ni = 0; ni < 4; ++ni)
#pragma unroll
      for (int ii = 0; ii < 4; ++ii)
        lw[(quad * 4 + ii) * 64 + ni * 16 + lm] = acc[mi][ni][ii];
#pragma unroll
    for (int j = 0; j < 4; ++j) {
      float4 v = *(const float4*)(lw + (j * 4 + r4) * 64 + c16 * 4);
      const int rowc = m0 + wm * 64 + mi * 16 + j * 4 + r4;
      if (rowc < cnt0) {
        const int R   = orig[rowc];            // uniform per 16-lane group
        const int col = n0 + wn * 64 + c16 * 4;
        *(float4*)(C + (size_t)R * Nd + col) = v;  // 16 lanes -> 256B contiguous
      }
    }
  }
}

extern "C" void kernel_launch(void* const* d_in, const int* in_sizes, int n_in,
                              void* d_out, int out_size, void* d_ws, size_t ws_size,
                              hipStream_t stream) {
  const int*   ids  = (const int*)d_in[0];
  // d_in[1] = lengths: unused (padding already encoded as -1 in ids)
  const float* Esem = (const float*)d_in[2];
  const float* vpr  = (const float*)d_in[3];
  const float* pw   = (const float*)d_in[4];

  float* out_emb   = (float*)d_out;                 // [M, Nd]
  float* out_amask = out_emb + (size_t)M * Nd;      // [M]
  float* out_tok   = out_amask + M;                 // [M]

  unsigned short* A  = (unsigned short*)d_ws;        // [<=M, Kd] bf16 (compact)
  unsigned short* Wb = A + (size_t)M * Kd;           // [Nd, Kd] bf16
  int* cid  = (int*)(Wb + (size_t)Nd * Kd);          // [M]
  int* orig = cid + M;                               // [M]
  int* inv  = orig + M;                              // [M]
  int* cnt  = inv + M;                               // [2]

  compact_kernel<<<1, 1024, 0, stream>>>(ids, cid, orig, inv, cnt, out_amask, out_tok);
  prep2_kernel<<<GATHER_BLOCKS + WCONV_BLOCKS, 256, 0, stream>>>(cid, cnt, Esem, vpr, pw, A, Wb);
  gemm_kernel<<<GEMM_BLOCKS + ZB, 256, 0, stream>>>(A, Wb, orig, inv, cnt, out_emb);
}

// Round 2
// 494.607 us; speedup vs baseline: 1.0502x; 1.0309x over previous
//
#include <hip/hip_runtime.h>
#include <stdint.h>

// Problem constants (from reference)
constexpr int BB = 64, TT = 200;
constexpr int M  = BB * TT;          // 12800 rows
constexpr int DSEM = 768, DPR = 384;
constexpr int Kd = DSEM + DPR;       // 1152
constexpr int Nd = 2048;             // d_model
constexpr int NUM_ITEMS = 100000;
constexpr int BK = 64;               // K-tile

constexpr int GATHER_BLOCKS = (M * Kd / 8) / 256;   // 7200 (worst case, ~half exit)
constexpr int WCONV_BLOCKS  = (Nd * Kd / 8) / 256;  // 1152
constexpr int MASK_BLOCKS   = (M + 255) / 256;      // 50
constexpr int GEMM_BLOCKS   = (M / 128) * (Nd / 128); // 1600 (worst case)
constexpr int ZB            = 256;                  // zero-fill blocks appended to gemm grid

typedef short bf16x8 __attribute__((ext_vector_type(8)));  // 8 bf16 (4 VGPRs)
typedef unsigned short u16x8 __attribute__((ext_vector_type(8)));
typedef float f32x4  __attribute__((ext_vector_type(4)));

__device__ __forceinline__ unsigned short f2bf(float f) {
  union { float f; uint32_t u; } v; v.f = f;
  uint32_t u = v.u;
  u += 0x7fffu + ((u >> 16) & 1u);   // RNE
  return (unsigned short)(u >> 16);
}

// Key structural fact: setup masks ids to -1 exactly where t >= lengths[b], so
// valid  <=>  t < lengths[b]. Compaction geometry = prefix sum of 64 lengths.
// Each block recomputes it privately (256 B L2-hot load + 6-step wave scan) —
// no serial compaction kernel, no cross-block dependency.

// ---- K1 (prep): gather valid rows -> compact A (bf16) | proj_w -> bf16 | amask/tok
__global__ void prep_kernel(const int* __restrict__ ids,
                            const int* __restrict__ lens,
                            const float* __restrict__ Esem,
                            const float* __restrict__ vpr,
                            const float* __restrict__ pw,
                            unsigned short* __restrict__ A,
                            unsigned short* __restrict__ Wb,
                            int* __restrict__ orig,    // [cnt0] compact row -> original row
                            int* __restrict__ cnt,     // cnt[0] = valid count
                            float* __restrict__ amask,
                            float* __restrict__ tok) {
  const int b   = blockIdx.x;
  const int tid = threadIdx.x;
  if (b < GATHER_BLOCKS) {
    __shared__ int offs[65];           // exclusive prefix of lengths; offs[64]=cnt0
    if (tid < 64) {
      int x = lens[tid];               // lengths in [1, T]
#pragma unroll
      for (int d = 1; d < 64; d <<= 1) {
        int y = __shfl_up(x, d);
        if (tid >= d) x += y;
      }
      offs[tid + 1] = x;
      if (tid == 0) offs[0] = 0;
    }
    __syncthreads();
    const int cnt0 = offs[64];
    if (b == 0 && tid == 0) cnt[0] = cnt0;
    // 8 elems/thread: 144 chunks per compact row; chunk 96 splits sem|prompt exactly.
    unsigned g   = (unsigned)b * 256u + tid;
    unsigned row = g / 144u;
    if ((int)row >= cnt0) return;      // no further barriers: safe divergence
    unsigned chunk = g - row * 144u;
    unsigned col   = chunk * 8u;
    // batch index: largest bb with offs[bb] <= row (6-step search, broadcast reads)
    int lo = 0, hi = 63;
#pragma unroll
    for (int s = 0; s < 6; ++s) {
      int mid = (lo + hi + 1) >> 1;
      if (offs[mid] <= (int)row) lo = mid; else hi = mid - 1;
    }
    const int bb   = lo;
    const int t    = (int)row - offs[bb];
    const int orow = bb * TT + t;
    if (chunk == 0) orig[row] = orow;  // one writer per compact row
    int id = ids[orow];                // valid by construction; clamp = OOB insurance
    id = (id >= 0 && id < NUM_ITEMS) ? id : 0;
    const float* src = (col < (unsigned)DSEM)
                         ? (Esem + (size_t)id * DSEM + col)
                         : (vpr  + (size_t)id * DPR  + (col - DSEM));
    float4 v0 = *(const float4*)src;
    float4 v1 = *(const float4*)(src + 4);
    u16x8 o;
    o[0] = f2bf(v0.x); o[1] = f2bf(v0.y); o[2] = f2bf(v0.z); o[3] = f2bf(v0.w);
    o[4] = f2bf(v1.x); o[5] = f2bf(v1.y); o[6] = f2bf(v1.z); o[7] = f2bf(v1.w);
    *(u16x8*)(A + (size_t)row * Kd + col) = o;   // single 16B store
  } else if (b < GATHER_BLOCKS + WCONV_BLOCKS) {
    int g = (b - GATHER_BLOCKS) * 256 + tid;
    int e = g * 8;
    float4 v0 = *(const float4*)(pw + e);
    float4 v1 = *(const float4*)(pw + e + 4);
    u16x8 o;
    o[0] = f2bf(v0.x); o[1] = f2bf(v0.y); o[2] = f2bf(v0.z); o[3] = f2bf(v0.w);
    o[4] = f2bf(v1.x); o[5] = f2bf(v1.y); o[6] = f2bf(v1.z); o[7] = f2bf(v1.w);
    *(u16x8*)(Wb + e) = o;
  } else {
    int i = (b - GATHER_BLOCKS - WCONV_BLOCKS) * 256 + tid;
    if (i < M) {
      int id = ids[i];
      bool valid = (id >= 0) && (id < NUM_ITEMS);
      amask[i] = valid ? 1.0f : 0.0f;
      tok[i]   = valid ? (float)id : -1.0f;   // id < 2^24: exact in f32
    }
  }
}

// ---- async 16B global->LDS (wave-uniform LDS base + lane*16 semantics)
__device__ __forceinline__ void async16(const void* gsrc, void* ldst) {
  __builtin_amdgcn_global_load_lds(
      (const __attribute__((address_space(1))) unsigned int*)gsrc,
      (__attribute__((address_space(3))) unsigned int*)ldst,
      16, 0, 0);
}

// ---- K2: C_compact[cnt0,Nd] = A @ Wb^T (bf16 MFMA), scattered to out rows,
//          plus ZB appended blocks zero-filling invalid out rows (from lengths).
// 128x128 tile, BK=64 (18 K-iters), 4 waves 2x2, wave = 64x64 via 4x4 MFMA 16x16x32.
// LDS XOR chunk swizzle: LDS chunk c of row r holds global chunk (c ^ (r&7)).
// XCD swizzle: xcd k = b&7 owns n-tiles {k, k+8}; block pairs the two n-blocks
// of one m-strip so the A-strip L2-hits on its second read.
__global__ __launch_bounds__(256) void gemm_kernel(const unsigned short* __restrict__ A,
                                                   const unsigned short* __restrict__ Wb,
                                                   const int* __restrict__ orig,
                                                   const int* __restrict__ lens,
                                                   const int* __restrict__ cnt,
                                                   float* __restrict__ C) {
  __shared__ __align__(16) unsigned short lds_a[128 * BK];  // 16 KB
  __shared__ __align__(16) unsigned short lds_b[128 * BK];  // 16 KB

  const int tid = threadIdx.x;

  if (blockIdx.x >= GEMM_BLOCKS) {
    // zero-fill invalid output rows directly from lengths: rows (b, t>=len[b]).
    const int zb  = blockIdx.x - GEMM_BLOCKS;   // 0..255
    const int bb  = zb & 63;
    const int j0  = zb >> 6;                    // 0..3
    const int len = lens[bb];
    const float4 z4 = {0.f, 0.f, 0.f, 0.f};
    for (int t = len + j0; t < TT; t += 4) {
      float* dst = C + (size_t)(bb * TT + t) * Nd + tid * 8;
      *(float4*)dst       = z4;                 // 256 thr x 32B = full 8KB row
      *(float4*)(dst + 4) = z4;
    }
    return;
  }

  const int cnt0   = cnt[0];
  const int strips = (cnt0 + 127) >> 7;

  const int b  = blockIdx.x;       // 0..1599
  const int k8 = b & 7;
  const int i  = b >> 3;           // 0..199
  if ((i >> 1) >= strips) return;  // block-uniform: inactive strip, exit before barriers
  const int m0 = (i >> 1) * 128;                // compact m-strip
  const int n0 = (k8 + 8 * (i & 1)) * 128;      // n-tile: {k8, k8+8}

  const int lane = tid & 63;
  const int wave = tid >> 6;
  const int wm = wave >> 1, wn = wave & 1;
  const int quad = lane >> 4, lm = lane & 15;

  // staging: slot idx = r*256 + tid -> LDS row = idx>>3, chunk = idx&7 (8 elems)
  const int srow   = tid >> 3;   // + r*32
  const int schunk = tid & 7;

  f32x4 acc[4][4];
#pragma unroll
  for (int i2 = 0; i2 < 4; ++i2)
#pragma unroll
    for (int j = 0; j < 4; ++j) acc[i2][j] = (f32x4){0.f, 0.f, 0.f, 0.f};

  for (int kt = 0; kt < Kd / BK; ++kt) {
    const int k0 = kt * BK;
#pragma unroll
    for (int r = 0; r < 4; ++r) {
      const int row = r * 32 + srow;
      const int gch = schunk ^ (row & 7);      // XOR swizzle (global side is per-lane)
      const unsigned short* ga = A + (size_t)(m0 + row) * Kd + k0 + gch * 8;
      async16(ga, lds_a + (size_t)(r * 256 + wave * 64) * 8);  // wave-uniform base
      const unsigned short* gb = Wb + (size_t)(n0 + row) * Kd + k0 + gch * 8;
      async16(gb, lds_b + (size_t)(r * 256 + wave * 64) * 8);
    }
    __syncthreads();

#pragma unroll
    for (int h = 0; h < 2; ++h) {              // two 32-wide k-slabs per BK=64
      bf16x8 af[4], bfr[4];
#pragma unroll
      for (int mi = 0; mi < 4; ++mi) {
        const int row = wm * 64 + mi * 16 + lm;
        af[mi] = *(const bf16x8*)(lds_a + row * BK + ((h * 4 + quad) ^ (row & 7)) * 8);
      }
#pragma unroll
      for (int ni = 0; ni < 4; ++ni) {
        const int row = wn * 64 + ni * 16 + lm;
        bfr[ni] = *(const bf16x8*)(lds_b + row * BK + ((h * 4 + quad) ^ (row & 7)) * 8);
      }
#pragma unroll
      for (int mi = 0; mi < 4; ++mi)
#pragma unroll
        for (int ni = 0; ni < 4; ++ni)
          acc[mi][ni] = __builtin_amdgcn_mfma_f32_16x16x32_bf16(af[mi], bfr[ni], acc[mi][ni], 0, 0, 0);
    }
    __syncthreads();
  }

  // ---- epilogue: same-wave LDS transpose -> coalesced dwordx4 stores,
  //      scattered through orig[] (stable compaction => monotone rows).
  float* lw = (float*)lds_a + wave * 1024;   // 16 rows x 64 cols f32, wave-private
  const int r4  = lane >> 4;     // 0..3
  const int c16 = lane & 15;     // 0..15
#pragma unroll
  for (int mi = 0; mi < 4; ++mi) {
    // C/D layout: col = lane&15, row = quad*4 + reg  [measured m89/m91]
#pragma unroll
    for (int ni = 0; ni < 4; ++ni)
#pragma unroll
      for (int ii = 0; ii < 4; ++ii)
        lw[(quad * 4 + ii) * 64 + ni * 16 + lm] = acc[mi][ni][ii];
#pragma unroll
    for (int j = 0; j < 4; ++j) {
      float4 v = *(const float4*)(lw + (j * 4 + r4) * 64 + c16 * 4);
      const int rowc = m0 + wm * 64 + mi * 16 + j * 4 + r4;
      if (rowc < cnt0) {
        const int R   = orig[rowc];            // uniform per 16-lane group
        const int col = n0 + wn * 64 + c16 * 4;
        *(float4*)(C + (size_t)R * Nd + col) = v;  // 16 lanes -> 256B contiguous
      }
    }
  }
}

extern "C" void kernel_launch(void* const* d_in, const int* in_sizes, int n_in,
                              void* d_out, int out_size, void* d_ws, size_t ws_size,
                              hipStream_t stream) {
  const int*   ids  = (const int*)d_in[0];
  const int*   lens = (const int*)d_in[1];
  const float* Esem = (const float*)d_in[2];
  const float* vpr  = (const float*)d_in[3];
  const float* pw   = (const float*)d_in[4];

  float* out_emb   = (float*)d_out;                 // [M, Nd]
  float* out_amask = out_emb + (size_t)M * Nd;      // [M]
  float* out_tok   = out_amask + M;                 // [M]

  unsigned short* A  = (unsigned short*)d_ws;        // [<=M, Kd] bf16 (compact)
  unsigned short* Wb = A + (size_t)M * Kd;           // [Nd, Kd] bf16
  int* orig = (int*)(Wb + (size_t)Nd * Kd);          // [M]
  int* cnt  = orig + M;                              // [1]

  prep_kernel<<<GATHER_BLOCKS + WCONV_BLOCKS + MASK_BLOCKS, 256, 0, stream>>>(
      ids, lens, Esem, vpr, pw, A, Wb, orig, cnt, out_amask, out_tok);
  gemm_kernel<<<GEMM_BLOCKS + ZB, 256, 0, stream>>>(A, Wb, orig, lens, cnt, out_emb);
}